// Round 3
// baseline (377.975 us; speedup 1.0000x reference)
//
#include <hip/hip_runtime.h>
#include <hip/hip_bf16.h>

#define B_ 8
#define N_ 1024
#define DIN 256
#define DOUT 256
#define R_ 4

typedef __attribute__((ext_vector_type(8))) short bf16x8;
typedef __attribute__((ext_vector_type(4))) float f32x4;
typedef __attribute__((ext_vector_type(4))) int i32x4;

__device__ __forceinline__ unsigned short f2bf(float f) {
    union { float f; unsigned int u; } v; v.f = f;
    unsigned int u = v.u;
    u += 0x7fffu + ((u >> 16) & 1u);
    return (unsigned short)(u >> 16);
}

// ---- k0: swizzle rel_w (f32 [R][D][K]) into bf16 MFMA B-fragment layout ----
// swzW[((r*8+ks)*16+nb)*512 + lane*8 + jj] = bf16(rw[r][nb*16+(lane&15)][ks*32+(lane>>4)*8+jj])
__global__ __launch_bounds__(256) void k0_swz(const float* __restrict__ rw,
                                              unsigned short* __restrict__ swzW) {
    int t = blockIdx.x * 256 + threadIdx.x;  // 0..32767
    int lane = t & 63, nb = (t >> 6) & 15, ks = (t >> 10) & 7, r = t >> 13;
    int m = lane & 15, q = lane >> 4;
    const float* src = rw + ((r * DOUT + nb * 16 + m) * DIN) + ks * 32 + q * 8;
    float4 v0 = *(const float4*)src;
    float4 v1 = *(const float4*)(src + 4);
    bf16x8 o;
    o[0] = (short)f2bf(v0.x); o[1] = (short)f2bf(v0.y);
    o[2] = (short)f2bf(v0.z); o[3] = (short)f2bf(v0.w);
    o[4] = (short)f2bf(v1.x); o[5] = (short)f2bf(v1.y);
    o[6] = (short)f2bf(v1.z); o[7] = (short)f2bf(v1.w);
    *(bf16x8*)(swzW + (long)t * 8) = o;
}

// ---- k1: feats = node @ rel_w^T + rel_b, written in B-fragment layout -------
// fswz[b][r][js][nb][lane'][8]: lane'=(q',m) holds feats[d=nb*16+m][j=js*32+q'*8+jj]
// plus fused ebf[b,r,n] = bf16(exp(sum_d feats[n][d]*attn_w[256+d]))
// grid 512 = (b,r,nt), 256 threads = 4 waves, wave = 16 rows of n.
__global__ __launch_bounds__(256) void k1_proj(const float* __restrict__ node,
        const unsigned short* __restrict__ swzW, const float* __restrict__ rel_b,
        const float* __restrict__ attn_w,
        unsigned short* __restrict__ fswz, unsigned short* __restrict__ ebf) {
    int bid = blockIdx.x;
    int nt = bid & 15, r = (bid >> 4) & 3, b = bid >> 6;
    int wave = threadIdx.x >> 6, lane = threadIdx.x & 63;
    int m = lane & 15, q = lane >> 4;
    int n0 = nt * 64 + wave * 16;

    const float* Abase = node + ((b * N_ + n0 + m) * DIN) + q * 8;
    const unsigned short* Wbase = swzW + r * 65536 + lane * 8;

    f32x4 acc[16];
#pragma unroll
    for (int i = 0; i < 16; i++) acc[i] = (f32x4)0.0f;

    for (int ks = 0; ks < 8; ks++) {
        float4 a0 = *(const float4*)(Abase + ks * 32);
        float4 a1 = *(const float4*)(Abase + ks * 32 + 4);
        bf16x8 af;
        af[0] = (short)f2bf(a0.x); af[1] = (short)f2bf(a0.y);
        af[2] = (short)f2bf(a0.z); af[3] = (short)f2bf(a0.w);
        af[4] = (short)f2bf(a1.x); af[5] = (short)f2bf(a1.y);
        af[6] = (short)f2bf(a1.z); af[7] = (short)f2bf(a1.w);
#pragma unroll
        for (int nb = 0; nb < 16; nb++) {
            bf16x8 bf = *(const bf16x8*)(Wbase + (ks * 16 + nb) * 512);
            acc[nb] = __builtin_amdgcn_mfma_f32_16x16x32_bf16(af, bf, acc[nb], 0, 0, 0);
        }
    }

    // C layout: row n = n0 + q*4 + reg, col d = nb*16 + m.
    int js = n0 >> 5;
    int jhi = (n0 >> 4) & 1;                  // which 16-half of the 32-j block
    int qp = jhi * 2 + (q >> 1);              // q' in fragment layout
    int jj0 = (q & 1) * 4;                    // jj of reg 0
    unsigned short* fb = fswz + ((long)((b * R_ + r) * 32 + js) * 16) * 512
                       + qp * 128 + m * 8 + jj0;

    float sj0 = 0.f, sj1 = 0.f, sj2 = 0.f, sj3 = 0.f;
#pragma unroll
    for (int nb = 0; nb < 16; nb++) {
        int d = nb * 16 + m;
        float bias = rel_b[r * DOUT + d];
        float aw = attn_w[DOUT + d];
        float v0 = acc[nb][0] + bias;
        float v1 = acc[nb][1] + bias;
        float v2 = acc[nb][2] + bias;
        float v3 = acc[nb][3] + bias;
        ushort4 o;
        o.x = f2bf(v0); o.y = f2bf(v1); o.z = f2bf(v2); o.w = f2bf(v3);
        *(ushort4*)(fb + nb * 512) = o;
        sj0 += v0 * aw; sj1 += v1 * aw; sj2 += v2 * aw; sj3 += v3 * aw;
    }
#pragma unroll
    for (int mk = 1; mk <= 8; mk <<= 1) {
        sj0 += __shfl_xor(sj0, mk, 64);
        sj1 += __shfl_xor(sj1, mk, 64);
        sj2 += __shfl_xor(sj2, mk, 64);
        sj3 += __shfl_xor(sj3, mk, 64);
    }
    if (m == 0) {
        ushort4 o;
        o.x = f2bf(__expf(sj0));
        o.y = f2bf(__expf(sj1));
        o.z = f2bf(__expf(sj2));
        o.w = f2bf(__expf(sj3));
        *(ushort4*)(ebf + (b * R_ + r) * N_ + n0 + q * 4) = o;
    }
}

// ---- k3: per-(b,r) masked softmax @ feats -> aggp[b,r,n,d] ------------------
// Barrier-free. B-frags are contiguous 1KB wave loads from fswz (L1-served,
// shared by all 4 waves). adj+e depth-2 register prefetch to keep the 134MB
// adj HBM stream saturated.
__global__ __launch_bounds__(256, 2) void k3_attn(const int* __restrict__ adj,
        const unsigned short* __restrict__ fswz, const unsigned short* __restrict__ ebf,
        float* __restrict__ aggp) {
    int bid = blockIdx.x;
    int it = bid & 15, r = (bid >> 4) & 3, b = bid >> 6;
    int t = threadIdx.x;
    int lane = t & 63, wave = t >> 6;
    int m = lane & 15, q = lane >> 4;
    int i0 = it * 64 + wave * 16;

    const int* adjbase = adj + (((b * R_ + r) * N_) + i0 + m) * (long)N_ + q * 8;
    const unsigned short* ebase = ebf + (b * R_ + r) * N_ + q * 8;
    const unsigned short* fbase = fswz + ((long)(b * R_ + r) * 32 * 16) * 512 + lane * 8;

    f32x4 acc[16];
#pragma unroll
    for (int i = 0; i < 16; i++) acc[i] = (f32x4)0.0f;
    float l = 0.f;

    i32x4 A0[2], A1[2];
    bf16x8 E[2];
    A0[0] = *(const i32x4*)(adjbase);      A1[0] = *(const i32x4*)(adjbase + 4);
    E[0]  = *(const bf16x8*)(ebase);
    A0[1] = *(const i32x4*)(adjbase + 32); A1[1] = *(const i32x4*)(adjbase + 36);
    E[1]  = *(const bf16x8*)(ebase + 32);

#pragma unroll 2
    for (int s = 0; s < 32; s++) {
        int cur = s & 1;
        int av[8] = {A0[cur].x, A0[cur].y, A0[cur].z, A0[cur].w,
                     A1[cur].x, A1[cur].y, A1[cur].z, A1[cur].w};
        const int* ei = (const int*)&E[cur];
        bf16x8 af;
        int* afi = (int*)&af;
#pragma unroll
        for (int p = 0; p < 4; p++) {
            unsigned int mask = (av[2*p] ? 0xffffu : 0u) | (av[2*p+1] ? 0xffff0000u : 0u);
            int me = ei[p] & (int)mask;
            afi[p] = me;
            union { int i; float f; } lo, hi;
            lo.i = me << 16;
            hi.i = me & (int)0xffff0000u;
            l += lo.f + hi.f;
        }
        // depth-2 prefetch (wraps refetch j=0/32 on last two iters; unused)
        int jn = ((s + 2) & 31) * 32;
        A0[cur] = *(const i32x4*)(adjbase + jn);
        A1[cur] = *(const i32x4*)(adjbase + jn + 4);
        E[cur]  = *(const bf16x8*)(ebase + jn);

        const unsigned short* fs = fbase + (long)s * 8192;
#pragma unroll
        for (int nb = 0; nb < 16; nb++) {
            bf16x8 bfq = *(const bf16x8*)(fs + nb * 512);
            acc[nb] = __builtin_amdgcn_mfma_f32_16x16x32_bf16(af, bfq, acc[nb], 0, 0, 0);
        }
    }

    // row-sum l: lanes {m, m+16, m+32, m+48} hold partial sums of row m
    l += __shfl_xor(l, 16, 64);
    l += __shfl_xor(l, 32, 64);
    float invl = (l > 0.f) ? 1.0f / l : 0.f;
    float invr[4];
#pragma unroll
    for (int reg = 0; reg < 4; reg++)
        invr[reg] = __shfl(invl, (lane >> 4) * 4 + reg, 64);

#pragma unroll
    for (int nb = 0; nb < 16; nb++) {
        int d = nb * 16 + m;
        float* outp = aggp + (((long)(b * R_ + r) * N_) + i0 + q * 4) * DOUT + d;
#pragma unroll
        for (int reg = 0; reg < 4; reg++)
            outp[reg * DOUT] = acc[nb][reg] * invr[reg];
    }
}

// ---- k4: out = sigmoid((sum_r aggp)·gw + gb) * sum_r aggp -------------------
__global__ __launch_bounds__(256) void k4_out(const float* __restrict__ aggp,
        const float* __restrict__ gate_w, const float* __restrict__ gate_b,
        float* __restrict__ out) {
    __shared__ float red[4];
    int bid = blockIdx.x;  // 8192 = b*1024 + n
    int n = bid & 1023, b = bid >> 10;
    int d = threadIdx.x;
    float s = 0.f;
#pragma unroll
    for (int r = 0; r < R_; r++)
        s += aggp[(((long)(b * R_ + r) * N_) + n) * DOUT + d];
    float v = s * gate_w[d];
#pragma unroll
    for (int off = 32; off; off >>= 1) v += __shfl_down(v, off, 64);
    int lane = d & 63, wave = d >> 6;
    if (lane == 0) red[wave] = v;
    __syncthreads();
    float tot = red[0] + red[1] + red[2] + red[3];
    float g = 1.f / (1.f + __expf(-(tot + gate_b[0])));
    out[((long)(b * N_ + n)) * DOUT + d] = g * s;
}

extern "C" void kernel_launch(void* const* d_in, const int* in_sizes, int n_in,
                              void* d_out, int out_size, void* d_ws, size_t ws_size,
                              hipStream_t stream) {
    const float* node   = (const float*)d_in[0];
    const int*   adj    = (const int*)d_in[1];
    const float* rel_w  = (const float*)d_in[2];
    const float* rel_b  = (const float*)d_in[3];
    const float* attn_w = (const float*)d_in[4];
    // d_in[5] = attn_b: cancels in softmax, unused
    const float* gate_w = (const float*)d_in[6];
    const float* gate_b = (const float*)d_in[7];
    float* out = (float*)d_out;

    char* ws = (char*)d_ws;
    unsigned short* swzW = (unsigned short*)ws;                        // 524,288 B
    unsigned short* fswz = (unsigned short*)(ws + 524288);             // 16,777,216 B
    unsigned short* ebf  = (unsigned short*)(ws + 524288 + 16777216);  // 65,536 B
    float*          aggp = (float*)(ws + 524288 + 16777216 + 65536);   // 33,554,432 B

    k0_swz<<<128, 256, 0, stream>>>(rel_w, swzW);
    k1_proj<<<512, 256, 0, stream>>>(node, swzW, rel_b, attn_w, fswz, ebf);
    k3_attn<<<512, 256, 0, stream>>>(adj, fswz, ebf, aggp);
    k4_out<<<8192, 256, 0, stream>>>(aggp, gate_w, gate_b, out);
}

// Round 4
// 264.286 us; speedup vs baseline: 1.4302x; 1.4302x over previous
//
#include <hip/hip_runtime.h>
#include <hip/hip_bf16.h>

#define B_ 8
#define N_ 1024
#define DIN 256
#define DOUT 256
#define R_ 4

typedef __attribute__((ext_vector_type(8))) short bf16x8;
typedef __attribute__((ext_vector_type(4))) float f32x4;
typedef __attribute__((ext_vector_type(4))) int i32x4;

__device__ __forceinline__ unsigned short f2bf(float f) {
    union { float f; unsigned int u; } v; v.f = f;
    unsigned int u = v.u;
    u += 0x7fffu + ((u >> 16) & 1u);
    return (unsigned short)(u >> 16);
}

// async global->LDS, 16B/lane. LDS dest = wave-uniform base + lane*16.
__device__ __forceinline__ void gl_lds16(const void* g, void* l) {
    __builtin_amdgcn_global_load_lds(
        (const __attribute__((address_space(1))) unsigned int*)g,
        (__attribute__((address_space(3))) unsigned int*)l, 16, 0, 0);
}

// ---- k0: swizzle rel_w (f32 [R][D][K]) into bf16 MFMA B-fragment layout ----
__global__ __launch_bounds__(256) void k0_swz(const float* __restrict__ rw,
                                              unsigned short* __restrict__ swzW) {
    int t = blockIdx.x * 256 + threadIdx.x;  // 0..32767
    int lane = t & 63, nb = (t >> 6) & 15, ks = (t >> 10) & 7, r = t >> 13;
    int m = lane & 15, q = lane >> 4;
    const float* src = rw + ((r * DOUT + nb * 16 + m) * DIN) + ks * 32 + q * 8;
    float4 v0 = *(const float4*)src;
    float4 v1 = *(const float4*)(src + 4);
    bf16x8 o;
    o[0] = (short)f2bf(v0.x); o[1] = (short)f2bf(v0.y);
    o[2] = (short)f2bf(v0.z); o[3] = (short)f2bf(v0.w);
    o[4] = (short)f2bf(v1.x); o[5] = (short)f2bf(v1.y);
    o[6] = (short)f2bf(v1.z); o[7] = (short)f2bf(v1.w);
    *(bf16x8*)(swzW + (long)t * 8) = o;
}

// ---- k1: G[j][d] = e[j]*(node@rel_w^T + rel_b)[j][d], B-fragment layout -----
// e[j] = exp(sum_d feats[j][d]*attn_w[256+d]); also stores ebf (bf16 e).
// W staged to LDS per-ks (double-buffered, global_load_lds); node reg-prefetch.
__global__ __launch_bounds__(256) void k1_proj(const float* __restrict__ node,
        const unsigned short* __restrict__ swzW, const float* __restrict__ rel_b,
        const float* __restrict__ attn_w,
        unsigned short* __restrict__ fswz, unsigned short* __restrict__ ebf) {
    __shared__ unsigned short Wbuf[2][8192];
    int bid = blockIdx.x;
    int nt = bid & 15, r = (bid >> 4) & 3, b = bid >> 6;
    int w = threadIdx.x >> 6, lane = threadIdx.x & 63;
    int m = lane & 15, q = lane >> 4;
    int n0 = nt * 64 + w * 16;

    const float* Abase = node + ((b * N_ + n0 + m) * DIN) + q * 8;
    const unsigned short* Wsrc = swzW + r * 65536;

#pragma unroll
    for (int i = 0; i < 4; i++)
        gl_lds16(Wsrc + (w * 4 + i) * 512 + lane * 8, &Wbuf[0][(w * 4 + i) * 512]);

    f32x4 acc[16];
#pragma unroll
    for (int i = 0; i < 16; i++) acc[i] = (f32x4)0.0f;

    float4 a0 = *(const float4*)(Abase);
    float4 a1 = *(const float4*)(Abase + 4);

    for (int ks = 0; ks < 8; ks++) {
        int cur = ks & 1;
        __syncthreads();
        if (ks < 7) {
#pragma unroll
            for (int i = 0; i < 4; i++)
                gl_lds16(Wsrc + ((ks + 1) * 16 + w * 4 + i) * 512 + lane * 8,
                         &Wbuf[cur ^ 1][(w * 4 + i) * 512]);
        }
        bf16x8 af;
        af[0] = (short)f2bf(a0.x); af[1] = (short)f2bf(a0.y);
        af[2] = (short)f2bf(a0.z); af[3] = (short)f2bf(a0.w);
        af[4] = (short)f2bf(a1.x); af[5] = (short)f2bf(a1.y);
        af[6] = (short)f2bf(a1.z); af[7] = (short)f2bf(a1.w);
        if (ks < 7) {
            a0 = *(const float4*)(Abase + (ks + 1) * 32);
            a1 = *(const float4*)(Abase + (ks + 1) * 32 + 4);
        }
#pragma unroll
        for (int nb = 0; nb < 16; nb++) {
            bf16x8 wf = *(const bf16x8*)(&Wbuf[cur][nb * 512 + lane * 8]);
            acc[nb] = __builtin_amdgcn_mfma_f32_16x16x32_bf16(af, wf, acc[nb], 0, 0, 0);
        }
    }

    // C layout: row j = n0 + q*4 + reg, col d = nb*16 + m.
    float sj0 = 0.f, sj1 = 0.f, sj2 = 0.f, sj3 = 0.f;
    float bias[16], aw[16];
#pragma unroll
    for (int nb = 0; nb < 16; nb++) {
        int d = nb * 16 + m;
        bias[nb] = rel_b[r * DOUT + d];
        aw[nb] = attn_w[DOUT + d];
        sj0 += (acc[nb][0] + bias[nb]) * aw[nb];
        sj1 += (acc[nb][1] + bias[nb]) * aw[nb];
        sj2 += (acc[nb][2] + bias[nb]) * aw[nb];
        sj3 += (acc[nb][3] + bias[nb]) * aw[nb];
    }
#pragma unroll
    for (int mk = 1; mk <= 8; mk <<= 1) {
        sj0 += __shfl_xor(sj0, mk, 64);
        sj1 += __shfl_xor(sj1, mk, 64);
        sj2 += __shfl_xor(sj2, mk, 64);
        sj3 += __shfl_xor(sj3, mk, 64);
    }
    float e0 = __expf(sj0), e1 = __expf(sj1), e2 = __expf(sj2), e3 = __expf(sj3);

    int slice = b * R_ + r;
    int js = n0 >> 5;
    int jhi = (n0 >> 4) & 1;
    int qp = jhi * 2 + (q >> 1);
    int jj0 = (q & 1) * 4;
    unsigned short* fb = fswz + ((long)(slice * 32 + js) * 16) * 512
                       + qp * 128 + m * 8 + jj0;
#pragma unroll
    for (int nb = 0; nb < 16; nb++) {
        ushort4 o;
        o.x = f2bf((acc[nb][0] + bias[nb]) * e0);
        o.y = f2bf((acc[nb][1] + bias[nb]) * e1);
        o.z = f2bf((acc[nb][2] + bias[nb]) * e2);
        o.w = f2bf((acc[nb][3] + bias[nb]) * e3);
        *(ushort4*)(fb + nb * 512) = o;
    }
    if (m == 0) {
        ushort4 o;
        o.x = f2bf(e0); o.y = f2bf(e1); o.z = f2bf(e2); o.w = f2bf(e3);
        *(ushort4*)(ebf + slice * N_ + n0 + q * 4) = o;
    }
}

// ---- k3: agg = A @ G per slice (A = 0/1 adjacency as bf16), l = A @ e ------
// m97-style: double-buffered LDS staging via global_load_lds, 1 barrier/step.
// A-tile XOR-swizzled on the global-address side -> conflict-free ds_reads.
// XCD-aware bid swizzle keeps each XCD on 4 G-slices (L2-resident).
__global__ __launch_bounds__(256, 3) void k3_attn(const int* __restrict__ adj,
        const unsigned short* __restrict__ fswz, const unsigned short* __restrict__ ebf,
        float* __restrict__ aggp) {
    __shared__ unsigned short Gbuf[2][8192];  // 2 x 16KB: 16 frags of 1KB
    __shared__ int Abuf[2][2048];             // 2 x 8KB: 64 rows x 32 int32
    __shared__ unsigned short Ebuf[1024];     // 2KB: e-slice bf16

    int bid = blockIdx.x;
    int slice = (bid & 7) * 4 + ((bid >> 3) & 3);
    int it = bid >> 5;
    int t = threadIdx.x, lane = t & 63, w = t >> 6;
    int m = lane & 15, q = lane >> 4;
    int i0b = it * 64;

    const unsigned short* fsl = fswz + (size_t)slice * 262144;
    const int* adjsl = adj + (size_t)slice * (N_ * N_);
    const unsigned short* esl = ebf + slice * N_;

    int hh = lane >> 3, c = lane & 7;  // staging decomposition

    // prologue: stage step 0 + e-table
#pragma unroll
    for (int i = 0; i < 4; i++)
        gl_lds16(fsl + (w * 4 + i) * 512 + lane * 8, &Gbuf[0][(w * 4 + i) * 512]);
#pragma unroll
    for (int i = 0; i < 2; i++) {
        int g = w * 2 + i;
        gl_lds16(adjsl + ((size_t)(i0b + g * 8 + hh) << 10) + ((c ^ hh) << 2),
                 &Abuf[0][g * 256]);
    }
    if (w == 0) {
        gl_lds16(esl + lane * 8, &Ebuf[0]);
        gl_lds16(esl + 512 + lane * 8, &Ebuf[512]);
    }

    f32x4 acc[16];
#pragma unroll
    for (int i = 0; i < 16; i++) acc[i] = (f32x4)0.0f;
    float l = 0.f;

    int h = m & 7;
    int gr = w * 2 + (m >> 3);

    for (int s = 0; s < 32; s++) {
        int cur = s & 1;
        __syncthreads();
        if (s < 31) {
            int ns = s + 1;
#pragma unroll
            for (int i = 0; i < 4; i++)
                gl_lds16(fsl + (size_t)ns * 8192 + (w * 4 + i) * 512 + lane * 8,
                         &Gbuf[cur ^ 1][(w * 4 + i) * 512]);
#pragma unroll
            for (int i = 0; i < 2; i++) {
                int g = w * 2 + i;
                gl_lds16(adjsl + ((size_t)(i0b + g * 8 + hh) << 10) + ns * 32
                             + ((c ^ hh) << 2),
                         &Abuf[cur ^ 1][g * 256]);
            }
        }
        // A-frag: row w*16+m, cols s*32 + q*8 .. +7 (swizzled slots)
        const int* Ab = &Abuf[cur][gr * 256 + h * 32];
        i32x4 av0 = *(const i32x4*)(Ab + (((2 * q) ^ h) << 2));
        i32x4 av1 = *(const i32x4*)(Ab + (((2 * q + 1) ^ h) << 2));
        bf16x8 ev = *(const bf16x8*)(&Ebuf[s * 32 + q * 8]);

        int av[8] = {av0.x, av0.y, av0.z, av0.w, av1.x, av1.y, av1.z, av1.w};
        const int* ei = (const int*)&ev;
        bf16x8 af;
        int* afi = (int*)&af;
#pragma unroll
        for (int p = 0; p < 4; p++) {
            unsigned int msk = (av[2 * p] ? 0xffffu : 0u)
                             | (av[2 * p + 1] ? 0xffff0000u : 0u);
            afi[p] = (int)(msk & 0x3F803F80u);  // bf16 1.0/0.0 pair
            int me = ei[p] & (int)msk;          // masked e (bf16 pair)
            union { int i; float f; } lo, hi;
            lo.i = me << 16;
            hi.i = me & (int)0xffff0000u;
            l += lo.f + hi.f;
        }
        const unsigned short* Gb = &Gbuf[cur][lane * 8];
#pragma unroll
        for (int nb = 0; nb < 16; nb++) {
            bf16x8 bfq = *(const bf16x8*)(Gb + nb * 512);
            acc[nb] = __builtin_amdgcn_mfma_f32_16x16x32_bf16(af, bfq, acc[nb], 0, 0, 0);
        }
    }

    // l held per (row m, quarter q): reduce over q
    l += __shfl_xor(l, 16, 64);
    l += __shfl_xor(l, 32, 64);
    float invl = (l > 0.f) ? 1.0f / l : 0.f;
    float invr[4];
#pragma unroll
    for (int reg = 0; reg < 4; reg++)
        invr[reg] = __shfl(invl, (lane >> 4) * 4 + reg, 64);

    int i0 = i0b + w * 16;
#pragma unroll
    for (int nb = 0; nb < 16; nb++) {
        int d = nb * 16 + m;
        float* outp = aggp + (((long)slice * N_ + i0 + q * 4)) * DOUT + d;
#pragma unroll
        for (int reg = 0; reg < 4; reg++)
            outp[reg * DOUT] = acc[nb][reg] * invr[reg];
    }
}

// ---- k4: out = sigmoid((sum_r aggp)·gw + gb) * sum_r aggp -------------------
__global__ __launch_bounds__(256) void k4_out(const float* __restrict__ aggp,
        const float* __restrict__ gate_w, const float* __restrict__ gate_b,
        float* __restrict__ out) {
    __shared__ float red[4];
    int bid = blockIdx.x;  // 8192 = b*1024 + n
    int n = bid & 1023, b = bid >> 10;
    int d = threadIdx.x;
    float s = 0.f;
#pragma unroll
    for (int r = 0; r < R_; r++)
        s += aggp[(((long)(b * R_ + r) * N_) + n) * DOUT + d];
    float v = s * gate_w[d];
#pragma unroll
    for (int off = 32; off; off >>= 1) v += __shfl_down(v, off, 64);
    int lane = d & 63, wave = d >> 6;
    if (lane == 0) red[wave] = v;
    __syncthreads();
    float tot = red[0] + red[1] + red[2] + red[3];
    float g = 1.f / (1.f + __expf(-(tot + gate_b[0])));
    out[((long)(b * N_ + n)) * DOUT + d] = g * s;
}

extern "C" void kernel_launch(void* const* d_in, const int* in_sizes, int n_in,
                              void* d_out, int out_size, void* d_ws, size_t ws_size,
                              hipStream_t stream) {
    const float* node   = (const float*)d_in[0];
    const int*   adj    = (const int*)d_in[1];
    const float* rel_w  = (const float*)d_in[2];
    const float* rel_b  = (const float*)d_in[3];
    const float* attn_w = (const float*)d_in[4];
    // d_in[5] = attn_b: cancels in softmax, unused
    const float* gate_w = (const float*)d_in[6];
    const float* gate_b = (const float*)d_in[7];
    float* out = (float*)d_out;

    char* ws = (char*)d_ws;
    unsigned short* swzW = (unsigned short*)ws;                        // 524,288 B
    unsigned short* fswz = (unsigned short*)(ws + 524288);             // 16,777,216 B (G)
    unsigned short* ebf  = (unsigned short*)(ws + 524288 + 16777216);  // 65,536 B
    float*          aggp = (float*)(ws + 524288 + 16777216 + 65536);   // 33,554,432 B

    k0_swz<<<128, 256, 0, stream>>>(rel_w, swzW);
    k1_proj<<<512, 256, 0, stream>>>(node, swzW, rel_b, attn_w, fswz, ebf);
    k3_attn<<<512, 256, 0, stream>>>(adj, fswz, ebf, aggp);
    k4_out<<<8192, 256, 0, stream>>>(aggp, gate_w, gate_b, out);
}

// Round 5
// 252.646 us; speedup vs baseline: 1.4961x; 1.0461x over previous
//
#include <hip/hip_runtime.h>
#include <hip/hip_bf16.h>

#define B_ 8
#define N_ 1024
#define DIN 256
#define DOUT 256
#define R_ 4

typedef __attribute__((ext_vector_type(8))) short bf16x8;
typedef __attribute__((ext_vector_type(4))) float f32x4;
typedef __attribute__((ext_vector_type(4))) int i32x4;

__device__ __forceinline__ unsigned short f2bf(float f) {
    union { float f; unsigned int u; } v; v.f = f;
    unsigned int u = v.u;
    u += 0x7fffu + ((u >> 16) & 1u);
    return (unsigned short)(u >> 16);
}
__device__ __forceinline__ float bf2f(unsigned short h) {
    union { float f; unsigned int u; } v; v.u = ((unsigned int)h) << 16;
    return v.f;
}

// async global->LDS, 16B/lane. LDS dest = wave-uniform base + lane*16.
__device__ __forceinline__ void gl_lds16(const void* g, void* l) {
    __builtin_amdgcn_global_load_lds(
        (const __attribute__((address_space(1))) unsigned int*)g,
        (__attribute__((address_space(3))) unsigned int*)l, 16, 0, 0);
}

// ---- k0: swizzle rel_w (f32 [R][D][K]) into bf16 MFMA B-fragment layout ----
__global__ __launch_bounds__(256) void k0_swz(const float* __restrict__ rw,
                                              unsigned short* __restrict__ swzW) {
    int t = blockIdx.x * 256 + threadIdx.x;  // 0..32767
    int lane = t & 63, nb = (t >> 6) & 15, ks = (t >> 10) & 7, r = t >> 13;
    int m = lane & 15, q = lane >> 4;
    const float* src = rw + ((r * DOUT + nb * 16 + m) * DIN) + ks * 32 + q * 8;
    float4 v0 = *(const float4*)src;
    float4 v1 = *(const float4*)(src + 4);
    bf16x8 o;
    o[0] = (short)f2bf(v0.x); o[1] = (short)f2bf(v0.y);
    o[2] = (short)f2bf(v0.z); o[3] = (short)f2bf(v0.w);
    o[4] = (short)f2bf(v1.x); o[5] = (short)f2bf(v1.y);
    o[6] = (short)f2bf(v1.z); o[7] = (short)f2bf(v1.w);
    *(bf16x8*)(swzW + (long)t * 8) = o;
}

// ---- k1: G[j][d] = e[j]*(node@rel_w^T + rel_b)[j][d], B-fragment layout -----
// e[j] = exp(sum_d feats[j][d]*attn_w[256+d]); also stores ebf (bf16 e).
__global__ __launch_bounds__(256) void k1_proj(const float* __restrict__ node,
        const unsigned short* __restrict__ swzW, const float* __restrict__ rel_b,
        const float* __restrict__ attn_w,
        unsigned short* __restrict__ fswz, unsigned short* __restrict__ ebf) {
    __shared__ unsigned short Wbuf[2][8192];
    int bid = blockIdx.x;
    int nt = bid & 15, r = (bid >> 4) & 3, b = bid >> 6;
    int w = threadIdx.x >> 6, lane = threadIdx.x & 63;
    int m = lane & 15, q = lane >> 4;
    int n0 = nt * 64 + w * 16;

    const float* Abase = node + ((b * N_ + n0 + m) * DIN) + q * 8;
    const unsigned short* Wsrc = swzW + r * 65536;

#pragma unroll
    for (int i = 0; i < 4; i++)
        gl_lds16(Wsrc + (w * 4 + i) * 512 + lane * 8, &Wbuf[0][(w * 4 + i) * 512]);

    f32x4 acc[16];
#pragma unroll
    for (int i = 0; i < 16; i++) acc[i] = (f32x4)0.0f;

    float4 a0 = *(const float4*)(Abase);
    float4 a1 = *(const float4*)(Abase + 4);

    for (int ks = 0; ks < 8; ks++) {
        int cur = ks & 1;
        __syncthreads();
        if (ks < 7) {
#pragma unroll
            for (int i = 0; i < 4; i++)
                gl_lds16(Wsrc + ((ks + 1) * 16 + w * 4 + i) * 512 + lane * 8,
                         &Wbuf[cur ^ 1][(w * 4 + i) * 512]);
        }
        bf16x8 af;
        af[0] = (short)f2bf(a0.x); af[1] = (short)f2bf(a0.y);
        af[2] = (short)f2bf(a0.z); af[3] = (short)f2bf(a0.w);
        af[4] = (short)f2bf(a1.x); af[5] = (short)f2bf(a1.y);
        af[6] = (short)f2bf(a1.z); af[7] = (short)f2bf(a1.w);
        if (ks < 7) {
            a0 = *(const float4*)(Abase + (ks + 1) * 32);
            a1 = *(const float4*)(Abase + (ks + 1) * 32 + 4);
        }
#pragma unroll
        for (int nb = 0; nb < 16; nb++) {
            bf16x8 wf = *(const bf16x8*)(&Wbuf[cur][nb * 512 + lane * 8]);
            acc[nb] = __builtin_amdgcn_mfma_f32_16x16x32_bf16(af, wf, acc[nb], 0, 0, 0);
        }
    }

    // C layout: row j = n0 + q*4 + reg, col d = nb*16 + m.
    float sj0 = 0.f, sj1 = 0.f, sj2 = 0.f, sj3 = 0.f;
    float bias[16], aw[16];
#pragma unroll
    for (int nb = 0; nb < 16; nb++) {
        int d = nb * 16 + m;
        bias[nb] = rel_b[r * DOUT + d];
        aw[nb] = attn_w[DOUT + d];
        sj0 += (acc[nb][0] + bias[nb]) * aw[nb];
        sj1 += (acc[nb][1] + bias[nb]) * aw[nb];
        sj2 += (acc[nb][2] + bias[nb]) * aw[nb];
        sj3 += (acc[nb][3] + bias[nb]) * aw[nb];
    }
#pragma unroll
    for (int mk = 1; mk <= 8; mk <<= 1) {
        sj0 += __shfl_xor(sj0, mk, 64);
        sj1 += __shfl_xor(sj1, mk, 64);
        sj2 += __shfl_xor(sj2, mk, 64);
        sj3 += __shfl_xor(sj3, mk, 64);
    }
    float e0 = __expf(sj0), e1 = __expf(sj1), e2 = __expf(sj2), e3 = __expf(sj3);

    int slice = b * R_ + r;
    int js = n0 >> 5;
    int jhi = (n0 >> 4) & 1;
    int qp = jhi * 2 + (q >> 1);
    int jj0 = (q & 1) * 4;
    unsigned short* fb = fswz + ((long)(slice * 32 + js) * 16) * 512
                       + qp * 128 + m * 8 + jj0;
#pragma unroll
    for (int nb = 0; nb < 16; nb++) {
        ushort4 o;
        o.x = f2bf((acc[nb][0] + bias[nb]) * e0);
        o.y = f2bf((acc[nb][1] + bias[nb]) * e1);
        o.z = f2bf((acc[nb][2] + bias[nb]) * e2);
        o.w = f2bf((acc[nb][3] + bias[nb]) * e3);
        *(ushort4*)(fb + nb * 512) = o;
    }
    if (m == 0) {
        ushort4 o;
        o.x = f2bf(e0); o.y = f2bf(e1); o.z = f2bf(e2); o.w = f2bf(e3);
        *(ushort4*)(ebf + slice * N_ + n0 + q * 4) = o;
    }
}

// ---- k3: accU = A @ G over a j-HALF (unnormalized) + partial l = A @ e -----
// Only G rides the barrier path (16KB/step LDS dbuf via global_load_lds).
// adj: per-wave register prefetch depth-1. e: 1KB LDS table, loaded once.
// grid 1024 = slice(32) x it(16) x jh(2) -> 4 blocks/CU.
__global__ __launch_bounds__(256, 4) void k3_attn(const int* __restrict__ adj,
        const unsigned short* __restrict__ fswz, const unsigned short* __restrict__ ebf,
        unsigned short* __restrict__ aggU, float* __restrict__ lbuf) {
    __shared__ unsigned short Gbuf[2][8192];  // 2 x 16KB
    __shared__ unsigned short Ebuf[512];      // 1KB: this j-half's e

    int bid = blockIdx.x;
    int slice = (bid & 7) * 4 + ((bid >> 3) & 3);  // XCD-affine slice grouping
    int rest = bid >> 5;
    int it = rest & 15, jh = rest >> 4;
    int t = threadIdx.x, lane = t & 63, w = t >> 6;
    int m = lane & 15, q = lane >> 4;
    int i0b = it * 64;

    const unsigned short* fsl = fswz + ((size_t)(slice * 32 + jh * 16)) * 8192;
    const int* adjbase = adj + (size_t)slice * (N_ * N_)
                       + (size_t)(i0b + w * 16 + m) * N_ + jh * 512 + q * 8;
    const unsigned short* esl = ebf + slice * N_ + jh * 512;

    // prologue: stage G step 0, e-table, adj step 0
#pragma unroll
    for (int i = 0; i < 4; i++)
        gl_lds16(fsl + (w * 4 + i) * 512 + lane * 8, &Gbuf[0][(w * 4 + i) * 512]);
    if (w == 0)
        gl_lds16(esl + lane * 8, &Ebuf[0]);

    i32x4 A0c = *(const i32x4*)(adjbase);
    i32x4 A1c = *(const i32x4*)(adjbase + 4);

    f32x4 acc[16];
#pragma unroll
    for (int i = 0; i < 16; i++) acc[i] = (f32x4)0.0f;
    float l = 0.f;

    for (int s = 0; s < 16; s++) {
        int cur = s & 1;
        __syncthreads();  // drains staging for step s (and adj prefetch)
        i32x4 A0n, A1n;
        if (s < 15) {
#pragma unroll
            for (int i = 0; i < 4; i++)
                gl_lds16(fsl + (size_t)(s + 1) * 8192 + (w * 4 + i) * 512 + lane * 8,
                         &Gbuf[cur ^ 1][(w * 4 + i) * 512]);
            A0n = *(const i32x4*)(adjbase + (s + 1) * 32);
            A1n = *(const i32x4*)(adjbase + (s + 1) * 32 + 4);
        }
        bf16x8 ev = *(const bf16x8*)(&Ebuf[s * 32 + q * 8]);
        int av[8] = {A0c.x, A0c.y, A0c.z, A0c.w, A1c.x, A1c.y, A1c.z, A1c.w};
        const int* ei = (const int*)&ev;
        bf16x8 af;
        int* afi = (int*)&af;
#pragma unroll
        for (int p = 0; p < 4; p++) {
            unsigned int msk = (av[2 * p] ? 0xffffu : 0u)
                             | (av[2 * p + 1] ? 0xffff0000u : 0u);
            afi[p] = (int)(msk & 0x3F803F80u);  // A entries: bf16 1.0 / 0.0
            int me = ei[p] & (int)msk;          // masked e (bf16 pair) for l
            union { int i; float f; } lo, hi;
            lo.i = me << 16;
            hi.i = me & (int)0xffff0000u;
            l += lo.f + hi.f;
        }
        const unsigned short* Gb = &Gbuf[cur][lane * 8];
#pragma unroll
        for (int nb = 0; nb < 16; nb++) {
            bf16x8 bfq = *(const bf16x8*)(Gb + nb * 512);
            acc[nb] = __builtin_amdgcn_mfma_f32_16x16x32_bf16(af, bfq, acc[nb], 0, 0, 0);
        }
        A0c = A0n; A1c = A1n;
    }

    // partial l per row m: reduce over q
    l += __shfl_xor(l, 16, 64);
    l += __shfl_xor(l, 32, 64);
    int half = slice * 2 + jh;
    if (lane < 16)
        lbuf[half * N_ + i0b + w * 16 + lane] = l;

    // unnormalized accU (bf16): row = i0b + w*16 + q*4 + reg, col = nb*16 + m
    unsigned short* ob = aggU + ((size_t)half * N_ + i0b + w * 16 + q * 4) * DOUT + m;
#pragma unroll
    for (int nb = 0; nb < 16; nb++) {
#pragma unroll
        for (int reg = 0; reg < 4; reg++)
            ob[(size_t)reg * DOUT + nb * 16] = f2bf(acc[nb][reg]);
    }
}

// ---- k4: combine halves, gate, write out ------------------------------------
// s_d = sum_r (accU[r,0]+accU[r,1])_d / (l[r,0]+l[r,1]); out = sigmoid(s.gw+gb)*s
__global__ __launch_bounds__(256) void k4_out(const unsigned short* __restrict__ aggU,
        const float* __restrict__ lbuf, const float* __restrict__ gate_w,
        const float* __restrict__ gate_b, float* __restrict__ out) {
    __shared__ float red[4];
    int bid = blockIdx.x;  // 8192 = b*1024 + n
    int n = bid & 1023, b = bid >> 10;
    int d = threadIdx.x;
    float s = 0.f;
#pragma unroll
    for (int r = 0; r < R_; r++) {
        int sl = b * R_ + r;
        float a0 = bf2f(aggU[((size_t)(sl * 2 + 0) * N_ + n) * DOUT + d]);
        float a1 = bf2f(aggU[((size_t)(sl * 2 + 1) * N_ + n) * DOUT + d]);
        float lt = lbuf[(sl * 2 + 0) * N_ + n] + lbuf[(sl * 2 + 1) * N_ + n];
        float inv = (lt > 0.f) ? 1.0f / lt : 0.f;
        s += (a0 + a1) * inv;
    }
    float v = s * gate_w[d];
#pragma unroll
    for (int off = 32; off; off >>= 1) v += __shfl_down(v, off, 64);
    int lane = d & 63, wave = d >> 6;
    if (lane == 0) red[wave] = v;
    __syncthreads();
    float tot = red[0] + red[1] + red[2] + red[3];
    float g = 1.f / (1.f + __expf(-(tot + gate_b[0])));
    out[((long)(b * N_ + n)) * DOUT + d] = g * s;
}

extern "C" void kernel_launch(void* const* d_in, const int* in_sizes, int n_in,
                              void* d_out, int out_size, void* d_ws, size_t ws_size,
                              hipStream_t stream) {
    const float* node   = (const float*)d_in[0];
    const int*   adj    = (const int*)d_in[1];
    const float* rel_w  = (const float*)d_in[2];
    const float* rel_b  = (const float*)d_in[3];
    const float* attn_w = (const float*)d_in[4];
    // d_in[5] = attn_b: cancels in softmax, unused
    const float* gate_w = (const float*)d_in[6];
    const float* gate_b = (const float*)d_in[7];
    float* out = (float*)d_out;

    char* ws = (char*)d_ws;
    unsigned short* swzW = (unsigned short*)ws;                        // 524,288 B
    unsigned short* fswz = (unsigned short*)(ws + 524288);             // 16,777,216 B (G)
    unsigned short* ebf  = (unsigned short*)(ws + 17301504);           // 65,536 B
    unsigned short* aggU = (unsigned short*)(ws + 17367040);           // 33,554,432 B (bf16)
    float*          lbuf = (float*)(ws + 50921472);                    // 262,144 B

    k0_swz<<<128, 256, 0, stream>>>(rel_w, swzW);
    k1_proj<<<512, 256, 0, stream>>>(node, swzW, rel_b, attn_w, fswz, ebf);
    k3_attn<<<1024, 256, 0, stream>>>(adj, fswz, ebf, aggU, lbuf);
    k4_out<<<8192, 256, 0, stream>>>(aggU, lbuf, gate_w, gate_b, out);
}